// Round 1
// baseline (330.844 us; speedup 1.0000x reference)
//
#include <hip/hip_runtime.h>
#include <hip/hip_bf16.h>
#include <stdint.h>

#define LDIM 512
#define CDIM 128
#define NPOS (LDIM*LDIM)   // 262144 positions

typedef __attribute__((ext_vector_type(8))) short bf16x8;
typedef __attribute__((ext_vector_type(4))) float f32x4;

__device__ __forceinline__ unsigned short f2bf(float f) {
  union { __hip_bfloat16 h; unsigned short u; } cv;
  cv.h = __float2bfloat16(f);
  return cv.u;
}

__device__ __forceinline__ float sigm(float x) { return 1.0f / (1.0f + __expf(-x)); }

// async global->LDS, 16B per lane. LDS dest must be wave-uniform; HW adds lane*16.
__device__ __forceinline__ void gl_lds16(const unsigned short* g, unsigned short* l) {
  __builtin_amdgcn_global_load_lds(
      (const __attribute__((address_space(1))) unsigned int*)g,
      (__attribute__((address_space(3))) unsigned int*)l, 16, 0, 0);
}

// ---------------------------------------------------------------------------
// K0: transpose + convert 6 weight matrices (128x128 f32 [k][n]) into
// bf16 Wt[n][k], pre-swizzled: 16B chunk s stored at slot (s ^ (n&7)).
// Slots: 0=w_left 1=w_lgate 2=w_right 3=w_rgate 4=w_out 5=w_fgate
// ---------------------------------------------------------------------------
__global__ __launch_bounds__(256) void k_prep(
    const float* w0, const float* w1, const float* w2,
    const float* w3, const float* w4, const float* w5,
    unsigned short* wtall) {
  __shared__ float tmp[CDIM*CDIM];   // 64KB
  const float* w = (blockIdx.x==0)?w0:(blockIdx.x==1)?w1:(blockIdx.x==2)?w2:
                   (blockIdx.x==3)?w3:(blockIdx.x==4)?w4:w5;
  int t = threadIdx.x;
  #pragma unroll
  for (int m = 0; m < 16; ++m)
    ((float4*)tmp)[m*256 + t] = ((const float4*)w)[m*256 + t];
  __syncthreads();
  unsigned short* out = wtall + (size_t)blockIdx.x * (CDIM*CDIM);
  #pragma unroll
  for (int m = 0; m < 8; ++m) {
    int oc = m*256 + t;            // output 16B chunk index (n*16 + sc)
    int n = oc >> 4, sc = oc & 15;
    int s = sc ^ (n & 7);          // data chunk that lands in slot sc
    union { unsigned short u[8]; uint4 v; } pk;
    #pragma unroll
    for (int e = 0; e < 8; ++e) pk.u[e] = f2bf(tmp[(s*8 + e)*CDIM + n]);
    *(uint4*)(out + (size_t)oc*8) = pk.v;
  }
}

// ---------------------------------------------------------------------------
// KA: per block = 64 positions. LN(act) -> xs (LDS, swizzled) + xbf (global,
// swizzled). Then 2 passes (left pair, right pair): acc = xs @ W, gated,
// masked, written to leftT/rightT[c][pos] bf16 planes.
// ---------------------------------------------------------------------------
__global__ __launch_bounds__(256,3) void k_stageA(
    const float* __restrict__ act, const float* __restrict__ mask,
    const float* __restrict__ nscale, const float* __restrict__ nbias,
    const float* __restrict__ b_left, const float* __restrict__ b_lgate,
    const float* __restrict__ b_right, const float* __restrict__ b_rgate,
    const unsigned short* __restrict__ wtall,
    unsigned short* __restrict__ xbf,
    unsigned short* __restrict__ leftT,
    unsigned short* __restrict__ rightT) {
  __shared__ unsigned short xs[64*128];    // 16KB
  __shared__ unsigned short WB[128*128];   // 32KB
  const int t = threadIdx.x;
  const int wave = t >> 6, lane = t & 63;
  const int p0 = blockIdx.x * 64;

  // issue w_left load immediately
  #pragma unroll
  for (int m = 0; m < 8; ++m) {
    int qb = m*256 + wave*64;
    gl_lds16(wtall + (size_t)(qb + lane)*8, WB + qb*8);
  }

  // ---- LayerNorm: thread t holds c=[4*(t&31),+4) for pos = 8m + (t>>5)
  float4 av[8];
  const float4* actv = (const float4*)(act + (size_t)p0*CDIM);
  #pragma unroll
  for (int m = 0; m < 8; ++m) av[m] = actv[m*256 + t];
  const int q = t & 31, g8 = t >> 5;
  float4 ns = ((const float4*)nscale)[q];
  float4 nb = ((const float4*)nbias)[q];
  #pragma unroll
  for (int m = 0; m < 8; ++m) {
    float4 v = av[m];
    float s = v.x + v.y + v.z + v.w;
    float s2 = v.x*v.x + v.y*v.y + v.z*v.z + v.w*v.w;
    #pragma unroll
    for (int d = 1; d < 32; d <<= 1) { s += __shfl_xor(s, d); s2 += __shfl_xor(s2, d); }
    float mu = s * 0.0078125f;
    float rs = rsqrtf(fmaxf(s2 * 0.0078125f - mu*mu, 0.f) + 1e-5f);
    union { unsigned short u[4]; uint2 d2; } pk;
    pk.u[0] = f2bf((v.x - mu)*rs*ns.x + nb.x);
    pk.u[1] = f2bf((v.y - mu)*rs*ns.y + nb.y);
    pk.u[2] = f2bf((v.z - mu)*rs*ns.z + nb.z);
    pk.u[3] = f2bf((v.w - mu)*rs*ns.w + nb.w);
    int pos = m*8 + g8;
    int off = pos*128 + (((q >> 1) ^ (pos & 7)) * 8) + (q & 1)*4;  // swizzled
    *(uint2*)(xs + off) = pk.d2;
    *(uint2*)(xbf + (size_t)p0*128 + off) = pk.d2;
  }
  __syncthreads();   // xs + WB(w_left) ready

  // A fragments (row = pos, K = 128), persist across both passes
  bf16x8 afr[4];
  const int ar = wave*16 + (lane & 15), kg = lane >> 4, bn = lane & 15;
  #pragma unroll
  for (int ks = 0; ks < 4; ++ks)
    afr[ks] = *(const bf16x8*)(xs + ar*128 + (((ks*4 + kg) ^ (ar & 7)) * 8));

  const int rbase = wave*16 + ((lane >> 4) << 2);
  float pm[4];
  #pragma unroll
  for (int jj = 0; jj < 4; ++jj) {
    int p = p0 + rbase + jj;
    pm[jj] = mask[p >> 9] * mask[p & 511];
  }

  f32x4 accV[8], accG[8];
  const f32x4 fz = {0.f, 0.f, 0.f, 0.f};

  #pragma unroll
  for (int pass = 0; pass < 2; ++pass) {
    // value matmul (WB holds w_left / w_right)
    #pragma unroll
    for (int nf = 0; nf < 8; ++nf) {
      accV[nf] = fz;
      int n = nf*16 + bn;
      #pragma unroll
      for (int ks = 0; ks < 4; ++ks) {
        bf16x8 b = *(const bf16x8*)(WB + n*128 + (((ks*4 + kg) ^ (n & 7)) * 8));
        accV[nf] = __builtin_amdgcn_mfma_f32_16x16x32_bf16(afr[ks], b, accV[nf], 0, 0, 0);
      }
    }
    __syncthreads();            // done reading WB
    {
      const unsigned short* Wg = wtall + (size_t)(pass ? 3 : 1) * 16384;
      #pragma unroll
      for (int m = 0; m < 8; ++m) {
        int qb = m*256 + wave*64;
        gl_lds16(Wg + (size_t)(qb + lane)*8, WB + qb*8);
      }
    }
    __syncthreads();            // WB(gate weights) ready
    #pragma unroll
    for (int nf = 0; nf < 8; ++nf) {
      accG[nf] = fz;
      int n = nf*16 + bn;
      #pragma unroll
      for (int ks = 0; ks < 4; ++ks) {
        bf16x8 b = *(const bf16x8*)(WB + n*128 + (((ks*4 + kg) ^ (n & 7)) * 8));
        accG[nf] = __builtin_amdgcn_mfma_f32_16x16x32_bf16(afr[ks], b, accG[nf], 0, 0, 0);
      }
    }
    __syncthreads();            // done reading WB
    if (pass == 0) {            // prefetch w_right while epilogue stores fly
      const unsigned short* Wv = wtall + (size_t)2 * 16384;
      #pragma unroll
      for (int m = 0; m < 8; ++m) {
        int qb = m*256 + wave*64;
        gl_lds16(Wv + (size_t)(qb + lane)*8, WB + qb*8);
      }
    }
    // epilogue: gate + mask, write [c][pos] bf16 plane
    const float* bvp = pass ? b_right : b_left;
    const float* bgp = pass ? b_rgate : b_lgate;
    unsigned short* dst = pass ? rightT : leftT;
    #pragma unroll
    for (int nf = 0; nf < 8; ++nf) {
      int n = nf*16 + bn;
      float bv = bvp[n], bg = bgp[n];
      #pragma unroll
      for (int jj = 0; jj < 4; ++jj) {
        float val = (accV[nf][jj] + bv) * pm[jj];
        val *= sigm(accG[nf][jj] + bg);
        dst[(size_t)n*NPOS + p0 + rbase + jj] = f2bf(val);
      }
    }
    if (pass == 0) __syncthreads();   // WB(w_right) ready for pass 1
  }
}

// ---------------------------------------------------------------------------
// KB: einsum. Per block: one c-plane, 128x128 output tile, K=512.
// out[c][i][j] = sum_k L[c][i][k] * R[c][j][k]  (A-frag == B-frag pattern)
// ---------------------------------------------------------------------------
__global__ __launch_bounds__(256,3) void k_einsum(
    const unsigned short* __restrict__ leftT,
    const unsigned short* __restrict__ rightT,
    float* __restrict__ eout) {
  __shared__ unsigned short At[128*64];   // 16KB, row = 64 bf16 (8 chunks)
  __shared__ unsigned short Bt[128*64];
  const int t = threadIdx.x, wave = t >> 6, lane = t & 63;
  const int c = blockIdx.y;
  const int i0 = (blockIdx.x >> 2) * 128, j0 = (blockIdx.x & 3) * 128;
  const unsigned short* Lp = leftT + (size_t)c * NPOS;
  const unsigned short* Rp = rightT + (size_t)c * NPOS;
  const int wrow = (wave >> 1) * 64, wcol = (wave & 1) * 64;
  const int kg = lane >> 4, fr = lane & 15;

  f32x4 acc[4][4];
  const f32x4 fz = {0.f,0.f,0.f,0.f};
  #pragma unroll
  for (int a = 0; a < 4; ++a)
    #pragma unroll
    for (int b = 0; b < 4; ++b) acc[a][b] = fz;

  for (int kt = 0; kt < 8; ++kt) {
    #pragma unroll
    for (int m = 0; m < 4; ++m) {
      int qb = m*256 + wave*64;
      int qq = qb + lane;
      int r = qq >> 3;
      int kk = (qq & 7) ^ (r & 7);      // pre-swizzled global source
      gl_lds16(Lp + ((size_t)(i0 + r) << 9) + kt*64 + kk*8, At + qb*8);
      gl_lds16(Rp + ((size_t)(j0 + r) << 9) + kt*64 + kk*8, Bt + qb*8);
    }
    __syncthreads();
    #pragma unroll
    for (int ks = 0; ks < 2; ++ks) {
      bf16x8 af[4], bfr[4];
      #pragma unroll
      for (int mf = 0; mf < 4; ++mf) {
        int r = wrow + mf*16 + fr;
        af[mf] = *(const bf16x8*)(At + r*64 + (((ks*4 + kg) ^ (r & 7)) * 8));
      }
      #pragma unroll
      for (int nf = 0; nf < 4; ++nf) {
        int r = wcol + nf*16 + fr;
        bfr[nf] = *(const bf16x8*)(Bt + r*64 + (((ks*4 + kg) ^ (r & 7)) * 8));
      }
      #pragma unroll
      for (int mf = 0; mf < 4; ++mf)
        #pragma unroll
        for (int nf = 0; nf < 4; ++nf)
          acc[mf][nf] = __builtin_amdgcn_mfma_f32_16x16x32_bf16(af[mf], bfr[nf], acc[mf][nf], 0,0,0);
    }
    __syncthreads();
  }
  float* op = eout + (size_t)c * NPOS;
  const int rb = (lane >> 4) << 2;
  #pragma unroll
  for (int mf = 0; mf < 4; ++mf) {
    int row = i0 + wrow + mf*16 + rb;
    #pragma unroll
    for (int nf = 0; nf < 4; ++nf) {
      int col = j0 + wcol + nf*16 + fr;
      #pragma unroll
      for (int jj = 0; jj < 4; ++jj)
        op[(size_t)(row + jj)*LDIM + col] = acc[mf][nf][jj];
    }
  }
}

// ---------------------------------------------------------------------------
// KC: per block = 64 positions. LN(eout over c, fnorm affine) @ w_out + b_out,
// gated by sigmoid(x @ w_fgate + b_fgate). Writes final f32 [pos][c].
// ---------------------------------------------------------------------------
__global__ __launch_bounds__(256,2) void k_stageC(
    const float* __restrict__ eout,
    const unsigned short* __restrict__ xbf,
    const unsigned short* __restrict__ wtall,
    const float* __restrict__ fns, const float* __restrict__ fnb,
    const float* __restrict__ b_out, const float* __restrict__ b_fg,
    float* __restrict__ outp) {
  __shared__ unsigned short xs[64*128];    // 16KB: x tile, later ytile
  __shared__ unsigned short WB[128*128];   // 32KB
  const int t = threadIdx.x, wave = t >> 6, lane = t & 63;
  const int p0 = blockIdx.x * 64;

  #pragma unroll
  for (int m = 0; m < 4; ++m) {
    int qb = m*256 + wave*64;
    gl_lds16(xbf + (size_t)p0*128 + (size_t)(qb + lane)*8, xs + qb*8);
  }
  {
    const unsigned short* Wf = wtall + (size_t)5 * 16384;   // w_fgate
    #pragma unroll
    for (int m = 0; m < 8; ++m) {
      int qb = m*256 + wave*64;
      gl_lds16(Wf + (size_t)(qb + lane)*8, WB + qb*8);
    }
  }

  // eout loads: 4 lanes per position, lane handles c = [32*qq, +32)
  const int pos = t >> 2, qq = t & 3;
  float ev[32];
  const float* ep = eout + p0 + pos;
  #pragma unroll
  for (int j = 0; j < 32; ++j) ev[j] = ep[(size_t)(qq*32 + j) * NPOS];

  float s = 0.f, s2 = 0.f;
  #pragma unroll
  for (int j = 0; j < 32; ++j) { s += ev[j]; s2 += ev[j]*ev[j]; }
  s += __shfl_xor(s, 1); s2 += __shfl_xor(s2, 1);
  s += __shfl_xor(s, 2); s2 += __shfl_xor(s2, 2);
  float mu = s * 0.0078125f;
  float rs = rsqrtf(fmaxf(s2 * 0.0078125f - mu*mu, 0.f) + 1e-5f);
  unsigned short ybf[32];
  #pragma unroll
  for (int jc = 0; jc < 8; ++jc) {
    float4 fsv = ((const float4*)fns)[qq*8 + jc];
    float4 fbv = ((const float4*)fnb)[qq*8 + jc];
    ybf[jc*4+0] = f2bf((ev[jc*4+0]-mu)*rs*fsv.x + fbv.x);
    ybf[jc*4+1] = f2bf((ev[jc*4+1]-mu)*rs*fsv.y + fbv.y);
    ybf[jc*4+2] = f2bf((ev[jc*4+2]-mu)*rs*fsv.z + fbv.z);
    ybf[jc*4+3] = f2bf((ev[jc*4+3]-mu)*rs*fsv.w + fbv.w);
  }
  __syncthreads();   // xs + WB(w_fgate) ready

  const int ar = wave*16 + (lane & 15), kg = lane >> 4, bn = lane & 15;
  bf16x8 afr[4];
  #pragma unroll
  for (int ks = 0; ks < 4; ++ks)
    afr[ks] = *(const bf16x8*)(xs + ar*128 + (((ks*4 + kg) ^ (ar & 7)) * 8));

  f32x4 accG[8], accY[8];
  const f32x4 fz = {0.f,0.f,0.f,0.f};
  #pragma unroll
  for (int nf = 0; nf < 8; ++nf) {
    accG[nf] = fz;
    int n = nf*16 + bn;
    #pragma unroll
    for (int ks = 0; ks < 4; ++ks) {
      bf16x8 b = *(const bf16x8*)(WB + n*128 + (((ks*4 + kg) ^ (n & 7)) * 8));
      accG[nf] = __builtin_amdgcn_mfma_f32_16x16x32_bf16(afr[ks], b, accG[nf], 0,0,0);
    }
  }
  __syncthreads();   // everyone done reading xs + WB

  {
    const unsigned short* Wo = wtall + (size_t)4 * 16384;   // w_out
    #pragma unroll
    for (int m = 0; m < 8; ++m) {
      int qb = m*256 + wave*64;
      gl_lds16(Wo + (size_t)(qb + lane)*8, WB + qb*8);
    }
  }
  // write normalized ytile into xs (swizzled)
  #pragma unroll
  for (int cc = 0; cc < 4; ++cc) {
    int swz = ((qq*4 + cc) ^ (pos & 7));
    union { unsigned short u[8]; uint4 v; } pk;
    #pragma unroll
    for (int e = 0; e < 8; ++e) pk.u[e] = ybf[cc*8 + e];
    *(uint4*)(xs + pos*128 + swz*8) = pk.v;
  }
  __syncthreads();   // ytile + WB(w_out) ready

  bf16x8 yfr[4];
  #pragma unroll
  for (int ks = 0; ks < 4; ++ks)
    yfr[ks] = *(const bf16x8*)(xs + ar*128 + (((ks*4 + kg) ^ (ar & 7)) * 8));
  #pragma unroll
  for (int nf = 0; nf < 8; ++nf) {
    accY[nf] = fz;
    int n = nf*16 + bn;
    #pragma unroll
    for (int ks = 0; ks < 4; ++ks) {
      bf16x8 b = *(const bf16x8*)(WB + n*128 + (((ks*4 + kg) ^ (n & 7)) * 8));
      accY[nf] = __builtin_amdgcn_mfma_f32_16x16x32_bf16(yfr[ks], b, accY[nf], 0,0,0);
    }
  }

  const int rbase = wave*16 + ((lane >> 4) << 2);
  #pragma unroll
  for (int nf = 0; nf < 8; ++nf) {
    int n = nf*16 + bn;
    float bo = b_out[n], bfg = b_fg[n];
    #pragma unroll
    for (int jj = 0; jj < 4; ++jj) {
      float val = (accY[nf][jj] + bo) * sigm(accG[nf][jj] + bfg);
      outp[(size_t)(p0 + rbase + jj)*CDIM + n] = val;
    }
  }
}

// ---------------------------------------------------------------------------
extern "C" void kernel_launch(void* const* d_in, const int* in_sizes, int n_in,
                              void* d_out, int out_size, void* d_ws, size_t ws_size,
                              hipStream_t stream) {
  const float* act  = (const float*)d_in[0];
  const float* mask = (const float*)d_in[1];
  const float* nsc  = (const float*)d_in[2];
  const float* nbi  = (const float*)d_in[3];
  const float* w_l  = (const float*)d_in[4];
  const float* b_l  = (const float*)d_in[5];
  const float* w_r  = (const float*)d_in[6];
  const float* b_r  = (const float*)d_in[7];
  const float* w_lg = (const float*)d_in[8];
  const float* b_lg = (const float*)d_in[9];
  const float* w_rg = (const float*)d_in[10];
  const float* b_rg = (const float*)d_in[11];
  const float* fns  = (const float*)d_in[12];
  const float* fnb  = (const float*)d_in[13];
  const float* w_o  = (const float*)d_in[14];
  const float* b_o  = (const float*)d_in[15];
  const float* w_fg = (const float*)d_in[16];
  const float* b_fg = (const float*)d_in[17];
  float* outp = (float*)d_out;

  char* ws = (char*)d_ws;
  unsigned short* xbf    = (unsigned short*)ws;                         // 64MB bf16 x (swizzled)
  unsigned short* leftT  = (unsigned short*)(ws + ((size_t)64 << 20));  // 64MB [c][i*512+k]
  unsigned short* rightT = (unsigned short*)(ws + ((size_t)128 << 20)); // 64MB
  float* eout            = (float*)(ws + ((size_t)192 << 20));          // 128MB [c][i*512+j]
  unsigned short* wtall  = (unsigned short*)(ws + ((size_t)320 << 20)); // 192KB

  k_prep<<<6, 256, 0, stream>>>(w_l, w_lg, w_r, w_rg, w_o, w_fg, wtall);
  k_stageA<<<NPOS/64, 256, 0, stream>>>(act, mask, nsc, nbi, b_l, b_lg, b_r, b_rg,
                                        wtall, xbf, leftT, rightT);
  k_einsum<<<dim3(16, 128), 256, 0, stream>>>(leftT, rightT, eout);
  k_stageC<<<NPOS/64, 256, 0, stream>>>(eout, xbf, wtall, fns, fnb, b_o, b_fg, outp);
}

// Round 2
// 295.168 us; speedup vs baseline: 1.1209x; 1.1209x over previous
//
#include <hip/hip_runtime.h>
#include <hip/hip_bf16.h>
#include <stdint.h>

#define LDIM 512
#define CDIM 128
#define NPOS (LDIM*LDIM)   // 262144 positions

typedef __attribute__((ext_vector_type(8))) short bf16x8;
typedef __attribute__((ext_vector_type(4))) float f32x4;

__device__ __forceinline__ unsigned short f2bf(float f) {
  union { __hip_bfloat16 h; unsigned short u; } cv;
  cv.h = __float2bfloat16(f);
  return cv.u;
}

__device__ __forceinline__ float bf2f(unsigned short u) {
  union { unsigned int i; float f; } cv; cv.i = ((unsigned int)u) << 16; return cv.f;
}

__device__ __forceinline__ float sigm(float x) { return 1.0f / (1.0f + __expf(-x)); }

// async global->LDS, 16B per lane. LDS dest must be wave-uniform; HW adds lane*16.
__device__ __forceinline__ void gl_lds16(const unsigned short* g, unsigned short* l) {
  __builtin_amdgcn_global_load_lds(
      (const __attribute__((address_space(1))) unsigned int*)g,
      (__attribute__((address_space(3))) unsigned int*)l, 16, 0, 0);
}

// 8 MFMAs: acc[nf] = x(64x128) @ W(128 x 128), cols nf*16+bn. W chunk-swizzled.
__device__ __forceinline__ void mm8(const unsigned short* W, const bf16x8 afr[4],
                                    int bn, int kg, f32x4 acc[8]) {
  const f32x4 fz = {0.f,0.f,0.f,0.f};
  #pragma unroll
  for (int nf = 0; nf < 8; ++nf) {
    acc[nf] = fz;
    int n = nf*16 + bn;
    #pragma unroll
    for (int ks = 0; ks < 4; ++ks) {
      bf16x8 b = *(const bf16x8*)(W + n*128 + (((ks*4 + kg) ^ (n & 7)) * 8));
      acc[nf] = __builtin_amdgcn_mfma_f32_16x16x32_bf16(afr[ks], b, acc[nf], 0, 0, 0);
    }
  }
}

// ---------------------------------------------------------------------------
// K0: transpose + convert 6 weight matrices (128x128 f32 [k][n]) into
// bf16 Wt[n][k], pre-swizzled: 16B chunk s stored at slot (s ^ (n&7)).
// Slots: 0=w_left 1=w_lgate 2=w_right 3=w_rgate 4=w_out 5=w_fgate
// ---------------------------------------------------------------------------
__global__ __launch_bounds__(256) void k_prep(
    const float* w0, const float* w1, const float* w2,
    const float* w3, const float* w4, const float* w5,
    unsigned short* wtall) {
  __shared__ float tmp[CDIM*CDIM];   // 64KB
  const float* w = (blockIdx.x==0)?w0:(blockIdx.x==1)?w1:(blockIdx.x==2)?w2:
                   (blockIdx.x==3)?w3:(blockIdx.x==4)?w4:w5;
  int t = threadIdx.x;
  #pragma unroll
  for (int m = 0; m < 16; ++m)
    ((float4*)tmp)[m*256 + t] = ((const float4*)w)[m*256 + t];
  __syncthreads();
  unsigned short* out = wtall + (size_t)blockIdx.x * (CDIM*CDIM);
  #pragma unroll
  for (int m = 0; m < 8; ++m) {
    int oc = m*256 + t;            // output 16B chunk index (n*16 + sc)
    int n = oc >> 4, sc = oc & 15;
    int s = sc ^ (n & 7);          // data chunk that lands in slot sc
    union { unsigned short u[8]; uint4 v; } pk;
    #pragma unroll
    for (int e = 0; e < 8; ++e) pk.u[e] = f2bf(tmp[(s*8 + e)*CDIM + n]);
    *(uint4*)(out + (size_t)oc*8) = pk.v;
  }
}

// ---------------------------------------------------------------------------
// KA: per block = 64 positions. LN(act) -> xs (LDS, swizzled) + xbf (global,
// swizzled). Double-buffered weights: WB0/WB1 = {left,lgate} then {right,rgate}.
// Epilogue goes through an LDS bounce so global stores are full 64B lines.
// ---------------------------------------------------------------------------
__global__ __launch_bounds__(256,2) void k_stageA(
    const float* __restrict__ act, const float* __restrict__ mask,
    const float* __restrict__ nscale, const float* __restrict__ nbias,
    const float* __restrict__ b_left, const float* __restrict__ b_lgate,
    const float* __restrict__ b_right, const float* __restrict__ b_rgate,
    const unsigned short* __restrict__ wtall,
    unsigned short* __restrict__ xbf,
    unsigned short* __restrict__ leftT,
    unsigned short* __restrict__ rightT) {
  __shared__ unsigned short xs[64*128];      // 16KB: x tile, then bounce [c=128][pos=64]
  __shared__ unsigned short WB[2][128*128];  // 64KB
  const int t = threadIdx.x;
  const int wave = t >> 6, lane = t & 63;
  const int p0 = blockIdx.x * 64;

  // issue w_left -> WB0, w_lgate -> WB1 immediately (DMA overlaps LN)
  #pragma unroll
  for (int m = 0; m < 8; ++m) {
    int qb = m*256 + wave*64;
    gl_lds16(wtall + (size_t)(qb + lane)*8, WB[0] + qb*8);
    gl_lds16(wtall + 16384 + (size_t)(qb + lane)*8, WB[1] + qb*8);
  }

  // ---- LayerNorm: thread t holds c=[4*(t&31),+4) for pos = 8m + (t>>5)
  float4 av[8];
  const float4* actv = (const float4*)(act + (size_t)p0*CDIM);
  #pragma unroll
  for (int m = 0; m < 8; ++m) av[m] = actv[m*256 + t];
  const int q = t & 31, g8 = t >> 5;
  float4 ns = ((const float4*)nscale)[q];
  float4 nb = ((const float4*)nbias)[q];
  #pragma unroll
  for (int m = 0; m < 8; ++m) {
    float4 v = av[m];
    float s = v.x + v.y + v.z + v.w;
    float s2 = v.x*v.x + v.y*v.y + v.z*v.z + v.w*v.w;
    #pragma unroll
    for (int d = 1; d < 32; d <<= 1) { s += __shfl_xor(s, d); s2 += __shfl_xor(s2, d); }
    float mu = s * 0.0078125f;
    float rs = rsqrtf(fmaxf(s2 * 0.0078125f - mu*mu, 0.f) + 1e-5f);
    union { unsigned short u[4]; uint2 d2; } pk;
    pk.u[0] = f2bf((v.x - mu)*rs*ns.x + nb.x);
    pk.u[1] = f2bf((v.y - mu)*rs*ns.y + nb.y);
    pk.u[2] = f2bf((v.z - mu)*rs*ns.z + nb.z);
    pk.u[3] = f2bf((v.w - mu)*rs*ns.w + nb.w);
    int pos = m*8 + g8;
    int off = pos*128 + (((q >> 1) ^ (pos & 7)) * 8) + (q & 1)*4;  // swizzled
    *(uint2*)(xs + off) = pk.d2;
    *(uint2*)(xbf + (size_t)p0*128 + off) = pk.d2;
  }
  __syncthreads();   // sync1: xs ready; vmcnt drained -> WB0/WB1 ready

  // A fragments (row = pos, K = 128), persist across both passes
  bf16x8 afr[4];
  const int ar = wave*16 + (lane & 15), kg = lane >> 4, bn = lane & 15;
  #pragma unroll
  for (int ks = 0; ks < 4; ++ks)
    afr[ks] = *(const bf16x8*)(xs + ar*128 + (((ks*4 + kg) ^ (ar & 7)) * 8));

  const int rbase = wave*16 + (kg << 2);
  float pm[4];
  #pragma unroll
  for (int jj = 0; jj < 4; ++jj) {
    int p = p0 + rbase + jj;
    pm[jj] = mask[p >> 9] * mask[p & 511];
  }

  f32x4 accV[8], accG[8];

  // ---- pass 0: left pair
  mm8(WB[0], afr, bn, kg, accV);
  mm8(WB[1], afr, bn, kg, accG);
  __syncthreads();   // sync2: done reading xs + WB

  // stage right pair
  #pragma unroll
  for (int m = 0; m < 8; ++m) {
    int qb = m*256 + wave*64;
    gl_lds16(wtall + 2*16384 + (size_t)(qb + lane)*8, WB[0] + qb*8);
    gl_lds16(wtall + 3*16384 + (size_t)(qb + lane)*8, WB[1] + qb*8);
  }

  // epilogue pass 0 -> bounce (bank-swizzled [c][pos])
  #pragma unroll
  for (int nf = 0; nf < 8; ++nf) {
    int n = nf*16 + bn;
    float bv = b_left[n], bg = b_lgate[n];
    #pragma unroll
    for (int jj = 0; jj < 4; ++jj) {
      int p = rbase + jj;
      float val = (accV[nf][jj] + bv) * pm[jj] * sigm(accG[nf][jj] + bg);
      xs[n*64 + ((((p >> 3) ^ (n & 7)) << 3)) + (p & 7)] = f2bf(val);
    }
  }
  __syncthreads();   // sync3: bounce ready; vmcnt drained -> right pair ready

  // coalesced plane writes for leftT (full 64B lines), then pass-1 MFMAs
  #pragma unroll
  for (int r = 0; r < 4; ++r) {
    int flat = r*256 + t;
    int c = flat >> 3, j = flat & 7;
    uint4 v = *(const uint4*)(xs + c*64 + ((j ^ (c & 7)) << 3));
    *(uint4*)(leftT + (size_t)c*NPOS + p0 + j*8) = v;
  }

  mm8(WB[0], afr, bn, kg, accV);
  mm8(WB[1], afr, bn, kg, accG);
  __syncthreads();   // sync4: done reading bounce (and WB)

  // epilogue pass 1 -> bounce
  #pragma unroll
  for (int nf = 0; nf < 8; ++nf) {
    int n = nf*16 + bn;
    float bv = b_right[n], bg = b_rgate[n];
    #pragma unroll
    for (int jj = 0; jj < 4; ++jj) {
      int p = rbase + jj;
      float val = (accV[nf][jj] + bv) * pm[jj] * sigm(accG[nf][jj] + bg);
      xs[n*64 + ((((p >> 3) ^ (n & 7)) << 3)) + (p & 7)] = f2bf(val);
    }
  }
  __syncthreads();   // sync5

  #pragma unroll
  for (int r = 0; r < 4; ++r) {
    int flat = r*256 + t;
    int c = flat >> 3, j = flat & 7;
    uint4 v = *(const uint4*)(xs + c*64 + ((j ^ (c & 7)) << 3));
    *(uint4*)(rightT + (size_t)c*NPOS + p0 + j*8) = v;
  }
}

// ---------------------------------------------------------------------------
// KB: einsum. Per block: one c-plane, 128x128 output tile, K=512, double-buffered.
// out[c][i][j] = sum_k L[c][i][k] * R[c][j][k]. Output bf16 via LDS bounce.
// ---------------------------------------------------------------------------
__global__ __launch_bounds__(256,2) void k_einsum(
    const unsigned short* __restrict__ leftT,
    const unsigned short* __restrict__ rightT,
    unsigned short* __restrict__ eout) {
  __shared__ unsigned short At[2][128*64];   // 2x16KB (also output bounce)
  __shared__ unsigned short Bt[2][128*64];
  const int t = threadIdx.x, wave = t >> 6, lane = t & 63;
  // XCD-chunked swizzle: 16 tiles of one c-plane stay on one XCD (2048 = 8*256)
  int fl = (blockIdx.x & 7) * 256 + (blockIdx.x >> 3);
  const int c = fl >> 4;
  const int i0 = ((fl >> 2) & 3) * 128, j0 = (fl & 3) * 128;
  const unsigned short* Lp = leftT + (size_t)c * NPOS;
  const unsigned short* Rp = rightT + (size_t)c * NPOS;
  const int wrow = (wave >> 1) * 64, wcol = (wave & 1) * 64;
  const int kg = lane >> 4, fr = lane & 15;

  f32x4 acc[4][4];
  const f32x4 fz = {0.f,0.f,0.f,0.f};
  #pragma unroll
  for (int a = 0; a < 4; ++a)
    #pragma unroll
    for (int b = 0; b < 4; ++b) acc[a][b] = fz;

  #define STAGE(buf, kt) do {                                              \
    _Pragma("unroll")                                                      \
    for (int m = 0; m < 4; ++m) {                                          \
      int qb = m*256 + wave*64;                                            \
      int qq = qb + lane;                                                  \
      int r = qq >> 3;                                                     \
      int kk = (qq & 7) ^ (r & 7);                                         \
      gl_lds16(Lp + ((size_t)(i0 + r) << 9) + (kt)*64 + kk*8, At[buf] + qb*8); \
      gl_lds16(Rp + ((size_t)(j0 + r) << 9) + (kt)*64 + kk*8, Bt[buf] + qb*8); \
    }                                                                      \
  } while (0)

  STAGE(0, 0);
  __syncthreads();
  int cur = 0;
  for (int kt = 0; kt < 8; ++kt) {
    if (kt < 7) STAGE(cur ^ 1, kt + 1);
    #pragma unroll
    for (int ks = 0; ks < 2; ++ks) {
      bf16x8 af[4], bfr[4];
      #pragma unroll
      for (int mf = 0; mf < 4; ++mf) {
        int r = wrow + mf*16 + fr;
        af[mf] = *(const bf16x8*)(At[cur] + r*64 + (((ks*4 + kg) ^ (r & 7)) * 8));
      }
      #pragma unroll
      for (int nf = 0; nf < 4; ++nf) {
        int r = wcol + nf*16 + fr;
        bfr[nf] = *(const bf16x8*)(Bt[cur] + r*64 + (((ks*4 + kg) ^ (r & 7)) * 8));
      }
      #pragma unroll
      for (int mf = 0; mf < 4; ++mf)
        #pragma unroll
        for (int nf = 0; nf < 4; ++nf)
          acc[mf][nf] = __builtin_amdgcn_mfma_f32_16x16x32_bf16(af[mf], bfr[nf], acc[mf][nf], 0,0,0);
    }
    __syncthreads();   // drains vmcnt (next tile staged) + all reads of cur done
    cur ^= 1;
  }
  #undef STAGE

  // epilogue: acc -> bounce (bank-swizzled [ri][ci]) -> full-line bf16 stores
  unsigned short* bounce = &At[0][0];   // 32KB
  const int rb = kg << 2;
  #pragma unroll
  for (int mf = 0; mf < 4; ++mf) {
    #pragma unroll
    for (int nf = 0; nf < 4; ++nf) {
      #pragma unroll
      for (int jj = 0; jj < 4; ++jj) {
        int ri = wrow + mf*16 + rb + jj;
        int ci = wcol + nf*16 + fr;
        bounce[ri*128 + (((ci >> 3) ^ (ri & 7)) << 3) + (ci & 7)] = f2bf(acc[mf][nf][jj]);
      }
    }
  }
  __syncthreads();
  unsigned short* op = eout + (size_t)c * NPOS;
  #pragma unroll
  for (int rr = 0; rr < 8; ++rr) {
    int flat = rr*256 + t;
    int row = flat >> 4, ch = flat & 15;
    uint4 v = *(const uint4*)(bounce + row*128 + ((ch ^ (row & 7)) << 3));
    *(uint4*)(op + (size_t)(i0 + row)*LDIM + j0 + ch*8) = v;
  }
}

// ---------------------------------------------------------------------------
// KC: per block = 64 positions. LN(eout over c, fnorm affine) @ w_out + b_out,
// gated by sigmoid(x @ w_fgate + b_fgate). Both weights staged up front.
// ---------------------------------------------------------------------------
__global__ __launch_bounds__(256,2) void k_stageC(
    const unsigned short* __restrict__ eout,
    const unsigned short* __restrict__ xbf,
    const unsigned short* __restrict__ wtall,
    const float* __restrict__ fns, const float* __restrict__ fnb,
    const float* __restrict__ b_out, const float* __restrict__ b_fg,
    float* __restrict__ outp) {
  __shared__ unsigned short xs[64*128];      // 16KB: x tile, later ytile
  __shared__ unsigned short WB[2][128*128];  // 64KB: WB0=w_fgate, WB1=w_out
  const int t = threadIdx.x, wave = t >> 6, lane = t & 63;
  const int p0 = blockIdx.x * 64;

  #pragma unroll
  for (int m = 0; m < 4; ++m) {
    int qb = m*256 + wave*64;
    gl_lds16(xbf + (size_t)p0*128 + (size_t)(qb + lane)*8, xs + qb*8);
  }
  #pragma unroll
  for (int m = 0; m < 8; ++m) {
    int qb = m*256 + wave*64;
    gl_lds16(wtall + 5*16384 + (size_t)(qb + lane)*8, WB[0] + qb*8);  // w_fgate
    gl_lds16(wtall + 4*16384 + (size_t)(qb + lane)*8, WB[1] + qb*8);  // w_out
  }

  // eout loads (bf16): 4 lanes per position, lane handles c = [32*qq, +32)
  const int pos = t >> 2, qq = t & 3;
  float ev[32];
  const unsigned short* ep = eout + p0 + pos;
  #pragma unroll
  for (int j = 0; j < 32; ++j) ev[j] = bf2f(ep[(size_t)(qq*32 + j) * NPOS]);

  float s = 0.f, s2 = 0.f;
  #pragma unroll
  for (int j = 0; j < 32; ++j) { s += ev[j]; s2 += ev[j]*ev[j]; }
  s += __shfl_xor(s, 1); s2 += __shfl_xor(s2, 1);
  s += __shfl_xor(s, 2); s2 += __shfl_xor(s2, 2);
  float mu = s * 0.0078125f;
  float rs = rsqrtf(fmaxf(s2 * 0.0078125f - mu*mu, 0.f) + 1e-5f);
  unsigned short ybf[32];
  #pragma unroll
  for (int jc = 0; jc < 8; ++jc) {
    float4 fsv = ((const float4*)fns)[qq*8 + jc];
    float4 fbv = ((const float4*)fnb)[qq*8 + jc];
    ybf[jc*4+0] = f2bf((ev[jc*4+0]-mu)*rs*fsv.x + fbv.x);
    ybf[jc*4+1] = f2bf((ev[jc*4+1]-mu)*rs*fsv.y + fbv.y);
    ybf[jc*4+2] = f2bf((ev[jc*4+2]-mu)*rs*fsv.z + fbv.z);
    ybf[jc*4+3] = f2bf((ev[jc*4+3]-mu)*rs*fsv.w + fbv.w);
  }
  __syncthreads();   // sync1: xs + WB0 + WB1 ready

  const int ar = wave*16 + (lane & 15), kg = lane >> 4, bn = lane & 15;
  bf16x8 afr[4];
  #pragma unroll
  for (int ks = 0; ks < 4; ++ks)
    afr[ks] = *(const bf16x8*)(xs + ar*128 + (((ks*4 + kg) ^ (ar & 7)) * 8));

  f32x4 accG[8], accY[8];
  mm8(WB[0], afr, bn, kg, accG);
  __syncthreads();   // sync2: everyone done reading xs

  // write normalized ytile into xs (swizzled)
  #pragma unroll
  for (int cc = 0; cc < 4; ++cc) {
    int swz = ((qq*4 + cc) ^ (pos & 7));
    union { unsigned short u[8]; uint4 v; } pk;
    #pragma unroll
    for (int e = 0; e < 8; ++e) pk.u[e] = ybf[cc*8 + e];
    *(uint4*)(xs + pos*128 + swz*8) = pk.v;
  }
  __syncthreads();   // sync3: ytile ready

  bf16x8 yfr[4];
  #pragma unroll
  for (int ks = 0; ks < 4; ++ks)
    yfr[ks] = *(const bf16x8*)(xs + ar*128 + (((ks*4 + kg) ^ (ar & 7)) * 8));
  mm8(WB[1], yfr, bn, kg, accY);

  const int rbase = wave*16 + (kg << 2);
  #pragma unroll
  for (int nf = 0; nf < 8; ++nf) {
    int n = nf*16 + bn;
    float bo = b_out[n], bfg = b_fg[n];
    #pragma unroll
    for (int jj = 0; jj < 4; ++jj) {
      float val = (accY[nf][jj] + bo) * sigm(accG[nf][jj] + bfg);
      outp[(size_t)(p0 + rbase + jj)*CDIM + n] = val;
    }
  }
}

// ---------------------------------------------------------------------------
extern "C" void kernel_launch(void* const* d_in, const int* in_sizes, int n_in,
                              void* d_out, int out_size, void* d_ws, size_t ws_size,
                              hipStream_t stream) {
  const float* act  = (const float*)d_in[0];
  const float* mask = (const float*)d_in[1];
  const float* nsc  = (const float*)d_in[2];
  const float* nbi  = (const float*)d_in[3];
  const float* w_l  = (const float*)d_in[4];
  const float* b_l  = (const float*)d_in[5];
  const float* w_r  = (const float*)d_in[6];
  const float* b_r  = (const float*)d_in[7];
  const float* w_lg = (const float*)d_in[8];
  const float* b_lg = (const float*)d_in[9];
  const float* w_rg = (const float*)d_in[10];
  const float* b_rg = (const float*)d_in[11];
  const float* fns  = (const float*)d_in[12];
  const float* fnb  = (const float*)d_in[13];
  const float* w_o  = (const float*)d_in[14];
  const float* b_o  = (const float*)d_in[15];
  const float* w_fg = (const float*)d_in[16];
  const float* b_fg = (const float*)d_in[17];
  float* outp = (float*)d_out;

  char* ws = (char*)d_ws;
  unsigned short* xbf    = (unsigned short*)ws;                         // 64MB bf16 x (swizzled)
  unsigned short* leftT  = (unsigned short*)(ws + ((size_t)64 << 20));  // 64MB [c][i*512+k]
  unsigned short* rightT = (unsigned short*)(ws + ((size_t)128 << 20)); // 64MB
  unsigned short* eout   = (unsigned short*)(ws + ((size_t)192 << 20)); // 64MB bf16 [c][i*512+j]
  unsigned short* wtall  = (unsigned short*)(ws + ((size_t)320 << 20)); // 192KB

  k_prep<<<6, 256, 0, stream>>>(w_l, w_lg, w_r, w_rg, w_o, w_fg, wtall);
  k_stageA<<<NPOS/64, 256, 0, stream>>>(act, mask, nsc, nbi, b_l, b_lg, b_r, b_rg,
                                        wtall, xbf, leftT, rightT);
  k_einsum<<<2048, 256, 0, stream>>>(leftT, rightT, eout);
  k_stageC<<<NPOS/64, 256, 0, stream>>>(eout, xbf, wtall, fns, fnb, b_o, b_fg, outp);
}